// Round 17
// baseline (169.054 us; speedup 1.0000x reference)
//
#include <hip/hip_runtime.h>
#include <hip/hip_bf16.h>

// Problem constants (B,T,C,H) = (4, 2048, 1024, 64)
#define B_ 4
#define T_ 2048
#define C_ 1024
#define H_ 64
#define M_ (B_ * T_)   // 8192 rows

// Attention geometry (R13): block = (b, q-group of 64 rows, chunk of 4
// k-tiles); nch(qg) = qg/4+1; blocks/batch = 144.
#define UPB2 144
#define NBLK (UPB2 * B_)   // 576

typedef __attribute__((ext_vector_type(8))) short short8v;  // 8 bf16 = 4 VGPRs
typedef __attribute__((ext_vector_type(4))) float f32x4;

static __device__ __forceinline__ short bf16_bits(float f) {
    return __builtin_bit_cast(short, __float2bfloat16(f));
}
static __device__ __forceinline__ float bf16_val(ushort u) {
    unsigned int i = ((unsigned int)u) << 16;
    return __builtin_bit_cast(float, i);
}

// ---------------------------------------------------------------------------
// Kernel 0: weights -> FRAGMENT-LINEAR bf16 layout (unchanged from R14/R15)
// + zero the 128 merge counters (runs before attn_part every launch, so the
// counters are deterministic across graph replays despite 0xAA poison).
// ---------------------------------------------------------------------------
__global__ __launch_bounds__(256) void w_transpose(
    const float* __restrict__ Wq,
    const float* __restrict__ Wk,
    const float* __restrict__ Wv,
    ushort* __restrict__ wtf,
    int* __restrict__ cnt)
{
    if (blockIdx.x == 0 && threadIdx.x < 128) cnt[threadIdx.x] = 0;

    const int idx  = blockIdx.x * 256 + threadIdx.x;   // 0..24575
    const int lane = idx & 63;
    const int ks   = (idx >> 6) & 31;
    const int cg   = idx >> 11;                        // 0..11
    const int col  = cg * 16 + (lane & 15);            // 0..191
    const int mat  = col >> 6;
    const int h    = col & 63;
    const int c0   = ks * 32 + (lane >> 4) * 8;
    const float* W = (mat == 0) ? Wq : (mat == 1) ? Wk : Wv;

    short8v o;
    #pragma unroll
    for (int j = 0; j < 8; ++j)
        o[j] = bf16_bits(W[(size_t)(c0 + j) * H_ + h]);
    *reinterpret_cast<short8v*>(&wtf[(size_t)idx * 8]) = o;
}

// ---------------------------------------------------------------------------
// Kernel 1: fused QKV projection — exact R15 version (measured-best: 50.9us
// config).  32 rows/wave, barrier-free 32-k-step loop, 64KB swizzled A_lds,
// fragment-linear wtf (one coalesced dwordx4 per B-fragment).
// mfma_f32_16x16x32_bf16 mapping (verified):
//   A: row=lane&15, k=(lane>>4)*8+i   B: col=lane&15, k=(lane>>4)*8+i
//   D: col=lane&15, row=(lane>>4)*4+reg
// ---------------------------------------------------------------------------
__global__ __launch_bounds__(768, 4) void qkv_mfma(
    const float* __restrict__ x,
    const ushort* __restrict__ wtf,    // fragment-linear, see w_transpose
    ushort* __restrict__ qb,
    ushort* __restrict__ kb,
    ushort* __restrict__ vtp)
{
    __shared__ __align__(16) ushort A_lds[32 * 1024];   // 64 KB, swizzled

    const int tid  = threadIdx.x;
    const int lane = tid & 63;
    const int wid  = tid >> 6;          // 0..11 = cg
    const int l15  = lane & 15;
    const int kg   = lane >> 4;
    const int row0 = blockIdx.x * 32;

    // ---- phase 1: stage x -> bf16 swizzled LDS (8192 f32x4 slots) ----
    #pragma unroll
    for (int p = 0; p < 11; ++p) {
        const int slot = tid + p * 768;
        if (slot < 8192) {
            const int srow = slot >> 8;            // 0..31
            const int c    = (slot & 255) * 4;     // f32 col 0..1020
            const f32x4 a = *reinterpret_cast<const f32x4*>(
                &x[(size_t)(row0 + srow) * C_ + c]);
            ushort4 ab;
            ab.x = (ushort)bf16_bits(a[0]); ab.y = (ushort)bf16_bits(a[1]);
            ab.z = (ushort)bf16_bits(a[2]); ab.w = (ushort)bf16_bits(a[3]);
            *reinterpret_cast<ushort4*>(
                (char*)A_lds + srow * 2048 + ((c * 2) ^ ((srow & 7) << 4))) = ab;
        }
    }
    __syncthreads();

    // ---- phase 2: barrier-free K loop ----
    f32x4 acc0 = {0.f, 0.f, 0.f, 0.f};
    f32x4 acc1 = {0.f, 0.f, 0.f, 0.f};

    const int r0 = l15;            // rows of fragment 0
    const int r1 = 16 + l15;       // rows of fragment 1
    char* const ab0 = (char*)A_lds + r0 * 2048;
    char* const ab1 = (char*)A_lds + r1 * 2048;
    const int swz0 = (r0 & 7) << 4;
    const int swz1 = (r1 & 7) << 4;

    #pragma unroll
    for (int ks = 0; ks < 32; ++ks) {
        const int off = ks * 64 + kg * 16;
        const short8v af0 = *reinterpret_cast<const short8v*>(ab0 + (off ^ swz0));
        const short8v af1 = *reinterpret_cast<const short8v*>(ab1 + (off ^ swz1));
        const short8v bf = *reinterpret_cast<const short8v*>(
            &wtf[((size_t)(wid * 32 + ks) * 64 + lane) * 8]);
        acc0 = __builtin_amdgcn_mfma_f32_16x16x32_bf16(af0, bf, acc0, 0, 0, 0);
        acc1 = __builtin_amdgcn_mfma_f32_16x16x32_bf16(af1, bf, acc1, 0, 0, 0);
    }
    __syncthreads();   // all waves done reading A_lds (about to alias it)

    // ---- epilogue: scatter acc into aliased LDS tiles ----
    ushort* q_s = A_lds;                 // [32][72]
    ushort* k_s = A_lds + 32 * 72;       // [32][72]
    ushort* v_s = A_lds + 64 * 72;       // [64][40]
    const float qscale = 0.03125f;  // 1024^-0.5
    {
        const int mat = wid >> 2;                 // 0=q 1=k 2=v (wave-uniform)
        const int h0  = (wid & 3) * 16;
        #pragma unroll
        for (int rt = 0; rt < 2; ++rt) {
            const f32x4 a = rt ? acc1 : acc0;
            #pragma unroll
            for (int j = 0; j < 4; ++j) {
                const int trow = rt * 16 + kg * 4 + j;   // 0..31
                if (mat == 0)      q_s[trow * 72 + h0 + l15] = (ushort)bf16_bits(a[j] * qscale);
                else if (mat == 1) k_s[trow * 72 + h0 + l15] = (ushort)bf16_bits(a[j]);
                else               v_s[(h0 + l15) * 40 + trow] = (ushort)bf16_bits(a[j]);
            }
        }
    }
    __syncthreads();

    if (tid < 512) {   // qb/kb: 32 rows x 16 ushort4 segs, one each
        const int row = tid >> 4;
        const int seg = tid & 15;
        const size_t o = (size_t)(row0 + row) * H_ + seg * 4;
        *reinterpret_cast<ushort4*>(&qb[o]) =
            *reinterpret_cast<const ushort4*>(&q_s[row * 72 + seg * 4]);
        *reinterpret_cast<ushort4*>(&kb[o]) =
            *reinterpret_cast<const ushort4*>(&k_s[row * 72 + seg * 4]);
    }
    if (tid >= 256) {  // vtp: 64 h x 8 ushort4 segs (32 t), one each
        const int slot = tid - 256;
        const int h    = slot >> 3;
        const int seg  = slot & 7;
        const int bb   = row0 >> 11;
        const int tt0  = row0 & (T_ - 1);
        *reinterpret_cast<ushort4*>(&vtp[((size_t)bb * H_ + h) * T_ + tt0 + seg * 4]) =
            *reinterpret_cast<const ushort4*>(&v_s[h * 40 + seg * 4]);
    }
}

// ---------------------------------------------------------------------------
// Kernel 2: split-K causal flash attention WITH FUSED MERGE.
// Compute path unchanged from R13-R16 (swapped-operand MFMA, LDS-staged K/V,
// bf16 partials).  New: after storing partials, each block does
// syncthreads -> threadfence (release) -> tid0 atomicAdd on the (b,qg)
// counter; the LAST block (old == nch-1) threadfences (acquire) and merges
// all partials for the 64-row q-group -> out.  No waiting/spinning, no
// dispatch-order assumption (G16-safe).  Saves the attn_merge dispatch+gap.
// Grid order flipped (long blocks first) for tail packing.
// ---------------------------------------------------------------------------
__global__ __launch_bounds__(256) void attn_part(
    const ushort* __restrict__ qb,
    const ushort* __restrict__ kb,
    const ushort* __restrict__ vtp,
    ushort* __restrict__ pOb,     // [NBLK][64 q][64 h] bf16
    float* __restrict__ pML,      // [NBLK][128]  (m rows 0-63, l rows 64-127)
    int* __restrict__ cnt,        // [B_*32] merge counters (zeroed upstream)
    float* __restrict__ out)
{
    __shared__ ushort K_lds[2][64][68];   // [key][h], padded
    __shared__ ushort V_lds[2][64][72];   // [h][key], padded
    __shared__ ushort p_lds[4][16][72];   // per-wave P^T tile [q][key]
    __shared__ int lastflag;

    const int tid  = threadIdx.x;
    const int wid  = tid >> 6;
    const int lane = tid & 63;
    const int l15  = lane & 15;
    const int g    = lane >> 4;

    // ---- block decode: b, qg (0..31), chunk.  bid flipped: long-first ----
    const int bid = (NBLK - 1) - blockIdx.x;
    const int b = bid / UPB2;
    const int u = bid - b * UPB2;
    int t = 0;
    #pragma unroll
    for (int tt = 1; tt < 8; ++tt)
        if (u >= 2 * tt * (tt + 1)) t = tt;
    const int rem   = u - 2 * t * (t + 1);
    const int s     = rem / (t + 1);
    const int chunk = rem - s * (t + 1);
    const int qg    = 4 * t + s;

    const int qt     = qg * 4 + wid;          // this wave's q-tile
    const int qrow0  = qt * 16;
    const int kt_lo  = chunk * 4;
    const int ntiles = min(4, qg + 1 - kt_lo);   // block-uniform, 1..4

    const ushort* kbase_b = kb  + (size_t)b * T_ * H_;
    const ushort* vbase_b = vtp + (size_t)b * H_ * T_;

    const ushort* qp = qb + ((size_t)(b * T_ + qrow0 + l15)) * H_ + g * 8;
    const short8v qf0 = *reinterpret_cast<const short8v*>(qp);
    const short8v qf1 = *reinterpret_cast<const short8v*>(qp + 32);

    const int srow[2] = { (tid + 0)   >> 3, (tid + 256) >> 3 };
    const int sseg[2] = { (tid + 0)   & 7,  (tid + 256) & 7  };

    {
        const ushort* ksrc = kbase_b + (size_t)kt_lo * 64 * H_;
        const ushort* vsrc = vbase_b + kt_lo * 64;
        #pragma unroll
        for (int j = 0; j < 2; ++j) {
            *reinterpret_cast<short8v*>(&K_lds[0][srow[j]][sseg[j] * 8]) =
                *reinterpret_cast<const short8v*>(&ksrc[srow[j] * H_ + sseg[j] * 8]);
            *reinterpret_cast<short8v*>(&V_lds[0][srow[j]][sseg[j] * 8]) =
                *reinterpret_cast<const short8v*>(&vsrc[(size_t)srow[j] * T_ + sseg[j] * 8]);
        }
    }
    __syncthreads();

    f32x4 accO[4];
    #pragma unroll
    for (int r = 0; r < 4; ++r) accO[r] = (f32x4){0.f, 0.f, 0.f, 0.f};
    float m = -1e30f, l = 0.f;

    #pragma unroll
    for (int i = 0; i < 4; ++i) {
        if (i >= ntiles) break;                 // block-uniform
        const int kt  = kt_lo + i;
        const int k0  = kt * 64;
        const int cur = i & 1, nxt = cur ^ 1;
        const bool havenext = (i + 1 < ntiles);

        short8v kreg[2], vreg[2];
        if (havenext) {
            const ushort* ksrc = kbase_b + (size_t)(kt + 1) * 64 * H_;
            const ushort* vsrc = vbase_b + (kt + 1) * 64;
            #pragma unroll
            for (int j = 0; j < 2; ++j) {
                kreg[j] = *reinterpret_cast<const short8v*>(&ksrc[srow[j] * H_ + sseg[j] * 8]);
                vreg[j] = *reinterpret_cast<const short8v*>(&vsrc[(size_t)srow[j] * T_ + sseg[j] * 8]);
            }
        }

        // ---- QK^T swapped from LDS ----
        f32x4 sv[4];
        #pragma unroll
        for (int c = 0; c < 4; ++c) {
            const short8v kf0 = *reinterpret_cast<const short8v*>(&K_lds[cur][c * 16 + l15][g * 8]);
            const short8v kf1 = *reinterpret_cast<const short8v*>(&K_lds[cur][c * 16 + l15][32 + g * 8]);
            sv[c] = (f32x4){0.f, 0.f, 0.f, 0.f};
            sv[c] = __builtin_amdgcn_mfma_f32_16x16x32_bf16(kf0, qf0, sv[c], 0, 0, 0);
            sv[c] = __builtin_amdgcn_mfma_f32_16x16x32_bf16(kf1, qf1, sv[c], 0, 0, 0);
        }

        if (kt == qg) {
            const int qrow = qrow0 + l15;
            #pragma unroll
            for (int c = 0; c < 4; ++c)
                #pragma unroll
                for (int r = 0; r < 4; ++r)
                    if (k0 + c * 16 + g * 4 + r > qrow) sv[c][r] = -1e30f;
        }

        // ---- per-lane softmax ----
        float mc[4];
        #pragma unroll
        for (int c = 0; c < 4; ++c)
            mc[c] = fmaxf(fmaxf(sv[c][0], sv[c][1]), fmaxf(sv[c][2], sv[c][3]));
        float tm = fmaxf(fmaxf(mc[0], mc[1]), fmaxf(mc[2], mc[3]));
        tm = fmaxf(tm, __shfl_xor(tm, 16));
        tm = fmaxf(tm, __shfl_xor(tm, 32));

        const float mn = fmaxf(m, tm);
        const float corr = __expf(m - mn);
        m = mn;
        #pragma unroll
        for (int ht = 0; ht < 4; ++ht)
            #pragma unroll
            for (int r = 0; r < 4; ++r)
                accO[ht][r] *= corr;

        float tsc[4];
        #pragma unroll
        for (int c = 0; c < 4; ++c) {
            const float p0 = __expf(sv[c][0] - m);
            const float p1 = __expf(sv[c][1] - m);
            const float p2 = __expf(sv[c][2] - m);
            const float p3 = __expf(sv[c][3] - m);
            tsc[c] = (p0 + p1) + (p2 + p3);
            ushort4 pk;
            pk.x = (ushort)bf16_bits(p0); pk.y = (ushort)bf16_bits(p1);
            pk.z = (ushort)bf16_bits(p2); pk.w = (ushort)bf16_bits(p3);
            *reinterpret_cast<ushort4*>(&p_lds[wid][l15][c * 16 + g * 4]) = pk;
        }
        float ts = (tsc[0] + tsc[1]) + (tsc[2] + tsc[3]);
        ts += __shfl_xor(ts, 16);
        ts += __shfl_xor(ts, 32);
        l = l * corr + ts;

        const short8v pb0 = *reinterpret_cast<const short8v*>(&p_lds[wid][l15][g * 8]);
        const short8v pb1 = *reinterpret_cast<const short8v*>(&p_lds[wid][l15][32 + g * 8]);

        // ---- PV swapped from LDS ----
        #pragma unroll
        for (int ht = 0; ht < 4; ++ht) {
            const short8v vf0 = *reinterpret_cast<const short8v*>(&V_lds[cur][ht * 16 + l15][g * 8]);
            const short8v vf1 = *reinterpret_cast<const short8v*>(&V_lds[cur][ht * 16 + l15][32 + g * 8]);
            accO[ht] = __builtin_amdgcn_mfma_f32_16x16x32_bf16(vf0, pb0, accO[ht], 0, 0, 0);
            accO[ht] = __builtin_amdgcn_mfma_f32_16x16x32_bf16(vf1, pb1, accO[ht], 0, 0, 0);
        }

        if (havenext) {
            #pragma unroll
            for (int j = 0; j < 2; ++j) {
                *reinterpret_cast<short8v*>(&K_lds[nxt][srow[j]][sseg[j] * 8]) = kreg[j];
                *reinterpret_cast<short8v*>(&V_lds[nxt][srow[j]][sseg[j] * 8]) = vreg[j];
            }
        }
        __syncthreads();
    }

    // ---- partial store: bf16, one ushort4 per ht ----
    ushort* po = pOb + (size_t)bid * (64 * 64);
    #pragma unroll
    for (int ht = 0; ht < 4; ++ht) {
        ushort4 ov;
        ov.x = (ushort)bf16_bits(accO[ht][0]);
        ov.y = (ushort)bf16_bits(accO[ht][1]);
        ov.z = (ushort)bf16_bits(accO[ht][2]);
        ov.w = (ushort)bf16_bits(accO[ht][3]);
        *reinterpret_cast<ushort4*>(&po[(wid * 16 + l15) * 64 + ht * 16 + g * 4]) = ov;
    }
    if (g == 0) {
        pML[(size_t)bid * 128 + wid * 16 + l15]      = m;
        pML[(size_t)bid * 128 + 64 + wid * 16 + l15] = l;
    }

    // ---- fused merge: last-finisher for this (b,qg) merges ----
    __syncthreads();                 // all partial stores issued (vmcnt drained)
    __threadfence();                 // release: agent-scope writeback
    if (tid == 0) {
        const int old = atomicAdd(&cnt[b * 32 + qg], 1);
        lastflag = (old == t);       // nch-1 == t
    }
    __syncthreads();

    if (lastflag) {
        __threadfence();             // acquire: invalidate stale cached copies
        const int baseblk = b * UPB2 + 2 * t * (t + 1) + s * (t + 1);
        const int nch     = t + 1;
        const int h       = tid & 63;
        #pragma unroll 4
        for (int i = 0; i < 16; ++i) {
            const int row = wid * 16 + ((i + wid) & 15);   // 0..63, staggered
            float M = -1e30f;
            for (int uu = 0; uu < nch; ++uu)
                M = fmaxf(M, pML[(size_t)(baseblk + uu) * 128 + row]);
            float O = 0.f, L = 0.f;
            for (int uu = 0; uu < nch; ++uu) {
                const float w = __expf(pML[(size_t)(baseblk + uu) * 128 + row] - M);
                O += w * bf16_val(pOb[(size_t)(baseblk + uu) * 4096 + row * 64 + h]);
                L += w * pML[(size_t)(baseblk + uu) * 128 + 64 + row];
            }
            out[((size_t)(b * T_ + qg * 64 + row)) * H_ + h] = O / L;
        }
    }
}

// ---------------------------------------------------------------------------
// Launch. Input order is setup_inputs() dict order: x, Wk, Wq, Wv.
// ws: qb 1MB | kb 1MB | vtp 1MB | wtf 384KB | pOb 4.7MB | pML 295KB |
//     cnt 512B  (~8.4MB).  THREE dispatches (merge fused into attn_part).
// ---------------------------------------------------------------------------
extern "C" void kernel_launch(void* const* d_in, const int* in_sizes, int n_in,
                              void* d_out, int out_size, void* d_ws, size_t ws_size,
                              hipStream_t stream)
{
    const float* x  = (const float*)d_in[0];
    const float* Wk = (const float*)d_in[1];
    const float* Wq = (const float*)d_in[2];
    const float* Wv = (const float*)d_in[3];
    float* out = (float*)d_out;

    ushort* qbp = (ushort*)d_ws;                    // [M][64]
    ushort* kbp = qbp + (size_t)M_ * H_;            // [M][64]
    ushort* vtp = kbp + (size_t)M_ * H_;            // [B][64][T]
    ushort* wtf = vtp + (size_t)B_ * H_ * T_;       // fragment-linear weights
    ushort* pOb = wtf + (size_t)3 * H_ * C_;        // [NBLK][64][64] bf16
    float*  pML = (float*)(pOb + (size_t)NBLK * 64 * 64);  // [NBLK][128]
    int*    cnt = (int*)(pML + (size_t)NBLK * 128);        // [128]

    w_transpose<<<dim3(96), dim3(256), 0, stream>>>(Wq, Wk, Wv, wtf, cnt);
    qkv_mfma<<<dim3(M_ / 32), dim3(768), 0, stream>>>(x, wtf, qbp, kbp, vtp);
    attn_part<<<dim3(NBLK), dim3(256), 0, stream>>>(qbp, kbp, vtp, pOb, pML, cnt, out);
}

// Round 18
// 40.416 us; speedup vs baseline: 4.1828x; 4.1828x over previous
//
#include <hip/hip_runtime.h>
#include <hip/hip_bf16.h>

// Problem constants (B,T,C,H) = (4, 2048, 1024, 64)
#define B_ 4
#define T_ 2048
#define C_ 1024
#define H_ 64
#define M_ (B_ * T_)   // 8192 rows

// Attention geometry (R13): block = (b, q-group of 64 rows, chunk of 4
// k-tiles); nch(qg) = qg/4+1; blocks/batch = 144.
#define UPB2 144
#define NBLK (UPB2 * B_)   // 576

typedef __attribute__((ext_vector_type(8))) short short8v;  // 8 bf16 = 4 VGPRs
typedef __attribute__((ext_vector_type(4))) float f32x4;

static __device__ __forceinline__ short bf16_bits(float f) {
    return __builtin_bit_cast(short, __float2bfloat16(f));
}
static __device__ __forceinline__ float bf16_val(ushort u) {
    unsigned int i = ((unsigned int)u) << 16;
    return __builtin_bit_cast(float, i);
}

// ---------------------------------------------------------------------------
// Kernel 0: weights -> FRAGMENT-LINEAR bf16 layout (R14/R15 version, no
// counter zeroing — fused merge reverted after R17's fence disaster).
// wtf[((cg*32+ks)*64+lane)*8 + j] = W[c][h],  h-col = cg*16+(lane&15),
// c = ks*32+(lane>>4)*8+j.
// ---------------------------------------------------------------------------
__global__ __launch_bounds__(256) void w_transpose(
    const float* __restrict__ Wq,
    const float* __restrict__ Wk,
    const float* __restrict__ Wv,
    ushort* __restrict__ wtf)
{
    const int idx  = blockIdx.x * 256 + threadIdx.x;   // 0..24575
    const int lane = idx & 63;
    const int ks   = (idx >> 6) & 31;
    const int cg   = idx >> 11;                        // 0..11
    const int col  = cg * 16 + (lane & 15);            // 0..191
    const int mat  = col >> 6;
    const int h    = col & 63;
    const int c0   = ks * 32 + (lane >> 4) * 8;
    const float* W = (mat == 0) ? Wq : (mat == 1) ? Wk : Wv;

    short8v o;
    #pragma unroll
    for (int j = 0; j < 8; ++j)
        o[j] = bf16_bits(W[(size_t)(c0 + j) * H_ + h]);
    *reinterpret_cast<short8v*>(&wtf[(size_t)idx * 8]) = o;
}

// ---------------------------------------------------------------------------
// Kernel 1: fused QKV projection — exact R15 version (best measured, 50.9us
// config).  32 rows/wave, barrier-free 32-k-step loop, 64KB swizzled A_lds,
// fragment-linear wtf (one coalesced dwordx4 per B-fragment).
// mfma_f32_16x16x32_bf16 mapping (verified):
//   A: row=lane&15, k=(lane>>4)*8+i   B: col=lane&15, k=(lane>>4)*8+i
//   D: col=lane&15, row=(lane>>4)*4+reg
// ---------------------------------------------------------------------------
__global__ __launch_bounds__(768, 4) void qkv_mfma(
    const float* __restrict__ x,
    const ushort* __restrict__ wtf,    // fragment-linear, see w_transpose
    ushort* __restrict__ qb,
    ushort* __restrict__ kb,
    ushort* __restrict__ vtp)
{
    __shared__ __align__(16) ushort A_lds[32 * 1024];   // 64 KB, swizzled

    const int tid  = threadIdx.x;
    const int lane = tid & 63;
    const int wid  = tid >> 6;          // 0..11 = cg
    const int l15  = lane & 15;
    const int kg   = lane >> 4;
    const int row0 = blockIdx.x * 32;

    // ---- phase 1: stage x -> bf16 swizzled LDS (8192 f32x4 slots) ----
    #pragma unroll
    for (int p = 0; p < 11; ++p) {
        const int slot = tid + p * 768;
        if (slot < 8192) {
            const int srow = slot >> 8;            // 0..31
            const int c    = (slot & 255) * 4;     // f32 col 0..1020
            const f32x4 a = *reinterpret_cast<const f32x4*>(
                &x[(size_t)(row0 + srow) * C_ + c]);
            ushort4 ab;
            ab.x = (ushort)bf16_bits(a[0]); ab.y = (ushort)bf16_bits(a[1]);
            ab.z = (ushort)bf16_bits(a[2]); ab.w = (ushort)bf16_bits(a[3]);
            *reinterpret_cast<ushort4*>(
                (char*)A_lds + srow * 2048 + ((c * 2) ^ ((srow & 7) << 4))) = ab;
        }
    }
    __syncthreads();

    // ---- phase 2: barrier-free K loop ----
    f32x4 acc0 = {0.f, 0.f, 0.f, 0.f};
    f32x4 acc1 = {0.f, 0.f, 0.f, 0.f};

    const int r0 = l15;            // rows of fragment 0
    const int r1 = 16 + l15;       // rows of fragment 1
    char* const ab0 = (char*)A_lds + r0 * 2048;
    char* const ab1 = (char*)A_lds + r1 * 2048;
    const int swz0 = (r0 & 7) << 4;
    const int swz1 = (r1 & 7) << 4;

    #pragma unroll
    for (int ks = 0; ks < 32; ++ks) {
        const int off = ks * 64 + kg * 16;
        const short8v af0 = *reinterpret_cast<const short8v*>(ab0 + (off ^ swz0));
        const short8v af1 = *reinterpret_cast<const short8v*>(ab1 + (off ^ swz1));
        const short8v bf = *reinterpret_cast<const short8v*>(
            &wtf[((size_t)(wid * 32 + ks) * 64 + lane) * 8]);
        acc0 = __builtin_amdgcn_mfma_f32_16x16x32_bf16(af0, bf, acc0, 0, 0, 0);
        acc1 = __builtin_amdgcn_mfma_f32_16x16x32_bf16(af1, bf, acc1, 0, 0, 0);
    }
    __syncthreads();   // all waves done reading A_lds (about to alias it)

    // ---- epilogue: scatter acc into aliased LDS tiles ----
    ushort* q_s = A_lds;                 // [32][72]
    ushort* k_s = A_lds + 32 * 72;       // [32][72]
    ushort* v_s = A_lds + 64 * 72;       // [64][40]
    const float qscale = 0.03125f;  // 1024^-0.5
    {
        const int mat = wid >> 2;                 // 0=q 1=k 2=v (wave-uniform)
        const int h0  = (wid & 3) * 16;
        #pragma unroll
        for (int rt = 0; rt < 2; ++rt) {
            const f32x4 a = rt ? acc1 : acc0;
            #pragma unroll
            for (int j = 0; j < 4; ++j) {
                const int trow = rt * 16 + kg * 4 + j;   // 0..31
                if (mat == 0)      q_s[trow * 72 + h0 + l15] = (ushort)bf16_bits(a[j] * qscale);
                else if (mat == 1) k_s[trow * 72 + h0 + l15] = (ushort)bf16_bits(a[j]);
                else               v_s[(h0 + l15) * 40 + trow] = (ushort)bf16_bits(a[j]);
            }
        }
    }
    __syncthreads();

    if (tid < 512) {   // qb/kb: 32 rows x 16 ushort4 segs, one each
        const int row = tid >> 4;
        const int seg = tid & 15;
        const size_t o = (size_t)(row0 + row) * H_ + seg * 4;
        *reinterpret_cast<ushort4*>(&qb[o]) =
            *reinterpret_cast<const ushort4*>(&q_s[row * 72 + seg * 4]);
        *reinterpret_cast<ushort4*>(&kb[o]) =
            *reinterpret_cast<const ushort4*>(&k_s[row * 72 + seg * 4]);
    }
    if (tid >= 256) {  // vtp: 64 h x 8 ushort4 segs (32 t), one each
        const int slot = tid - 256;
        const int h    = slot >> 3;
        const int seg  = slot & 7;
        const int bb   = row0 >> 11;
        const int tt0  = row0 & (T_ - 1);
        *reinterpret_cast<ushort4*>(&vtp[((size_t)bb * H_ + h) * T_ + tt0 + seg * 4]) =
            *reinterpret_cast<const ushort4*>(&v_s[h * 40 + seg * 4]);
    }
}

// ---------------------------------------------------------------------------
// Kernel 2a: split-K causal flash attention (R13 compute path, no fences,
// no atomics).  Only delta vs R15: partial O stored as bf16 (validated
// R10/R16, absmax unchanged) -> halves partial traffic for merge.
// ---------------------------------------------------------------------------
__global__ __launch_bounds__(256) void attn_part(
    const ushort* __restrict__ qb,
    const ushort* __restrict__ kb,
    const ushort* __restrict__ vtp,
    ushort* __restrict__ pOb,     // [NBLK][64 q][64 h] bf16
    float* __restrict__ pML)      // [NBLK][128]  (m rows 0-63, l rows 64-127)
{
    __shared__ ushort K_lds[2][64][68];   // [key][h], padded
    __shared__ ushort V_lds[2][64][72];   // [h][key], padded
    __shared__ ushort p_lds[4][16][72];   // per-wave P^T tile [q][key]

    const int tid  = threadIdx.x;
    const int wid  = tid >> 6;
    const int lane = tid & 63;
    const int l15  = lane & 15;
    const int g    = lane >> 4;

    // ---- block decode: b, qg (0..31), chunk ----
    const int b = blockIdx.x / UPB2;
    const int u = blockIdx.x - b * UPB2;
    int t = 0;
    #pragma unroll
    for (int tt = 1; tt < 8; ++tt)
        if (u >= 2 * tt * (tt + 1)) t = tt;
    const int rem   = u - 2 * t * (t + 1);
    const int s     = rem / (t + 1);
    const int chunk = rem - s * (t + 1);
    const int qg    = 4 * t + s;

    const int qt     = qg * 4 + wid;          // this wave's q-tile
    const int qrow0  = qt * 16;
    const int kt_lo  = chunk * 4;
    const int ntiles = min(4, qg + 1 - kt_lo);   // block-uniform, 1..4

    const ushort* kbase_b = kb  + (size_t)b * T_ * H_;
    const ushort* vbase_b = vtp + (size_t)b * H_ * T_;

    const ushort* qp = qb + ((size_t)(b * T_ + qrow0 + l15)) * H_ + g * 8;
    const short8v qf0 = *reinterpret_cast<const short8v*>(qp);
    const short8v qf1 = *reinterpret_cast<const short8v*>(qp + 32);

    const int srow[2] = { (tid + 0)   >> 3, (tid + 256) >> 3 };
    const int sseg[2] = { (tid + 0)   & 7,  (tid + 256) & 7  };

    {
        const ushort* ksrc = kbase_b + (size_t)kt_lo * 64 * H_;
        const ushort* vsrc = vbase_b + kt_lo * 64;
        #pragma unroll
        for (int j = 0; j < 2; ++j) {
            *reinterpret_cast<short8v*>(&K_lds[0][srow[j]][sseg[j] * 8]) =
                *reinterpret_cast<const short8v*>(&ksrc[srow[j] * H_ + sseg[j] * 8]);
            *reinterpret_cast<short8v*>(&V_lds[0][srow[j]][sseg[j] * 8]) =
                *reinterpret_cast<const short8v*>(&vsrc[(size_t)srow[j] * T_ + sseg[j] * 8]);
        }
    }
    __syncthreads();

    f32x4 accO[4];
    #pragma unroll
    for (int r = 0; r < 4; ++r) accO[r] = (f32x4){0.f, 0.f, 0.f, 0.f};
    float m = -1e30f, l = 0.f;

    #pragma unroll
    for (int i = 0; i < 4; ++i) {
        if (i >= ntiles) break;                 // block-uniform
        const int kt  = kt_lo + i;
        const int k0  = kt * 64;
        const int cur = i & 1, nxt = cur ^ 1;
        const bool havenext = (i + 1 < ntiles);

        short8v kreg[2], vreg[2];
        if (havenext) {
            const ushort* ksrc = kbase_b + (size_t)(kt + 1) * 64 * H_;
            const ushort* vsrc = vbase_b + (kt + 1) * 64;
            #pragma unroll
            for (int j = 0; j < 2; ++j) {
                kreg[j] = *reinterpret_cast<const short8v*>(&ksrc[srow[j] * H_ + sseg[j] * 8]);
                vreg[j] = *reinterpret_cast<const short8v*>(&vsrc[(size_t)srow[j] * T_ + sseg[j] * 8]);
            }
        }

        // ---- QK^T swapped from LDS ----
        f32x4 sv[4];
        #pragma unroll
        for (int c = 0; c < 4; ++c) {
            const short8v kf0 = *reinterpret_cast<const short8v*>(&K_lds[cur][c * 16 + l15][g * 8]);
            const short8v kf1 = *reinterpret_cast<const short8v*>(&K_lds[cur][c * 16 + l15][32 + g * 8]);
            sv[c] = (f32x4){0.f, 0.f, 0.f, 0.f};
            sv[c] = __builtin_amdgcn_mfma_f32_16x16x32_bf16(kf0, qf0, sv[c], 0, 0, 0);
            sv[c] = __builtin_amdgcn_mfma_f32_16x16x32_bf16(kf1, qf1, sv[c], 0, 0, 0);
        }

        if (kt == qg) {
            const int qrow = qrow0 + l15;
            #pragma unroll
            for (int c = 0; c < 4; ++c)
                #pragma unroll
                for (int r = 0; r < 4; ++r)
                    if (k0 + c * 16 + g * 4 + r > qrow) sv[c][r] = -1e30f;
        }

        // ---- per-lane softmax ----
        float mc[4];
        #pragma unroll
        for (int c = 0; c < 4; ++c)
            mc[c] = fmaxf(fmaxf(sv[c][0], sv[c][1]), fmaxf(sv[c][2], sv[c][3]));
        float tm = fmaxf(fmaxf(mc[0], mc[1]), fmaxf(mc[2], mc[3]));
        tm = fmaxf(tm, __shfl_xor(tm, 16));
        tm = fmaxf(tm, __shfl_xor(tm, 32));

        const float mn = fmaxf(m, tm);
        const float corr = __expf(m - mn);
        m = mn;
        #pragma unroll
        for (int ht = 0; ht < 4; ++ht)
            #pragma unroll
            for (int r = 0; r < 4; ++r)
                accO[ht][r] *= corr;

        float tsc[4];
        #pragma unroll
        for (int c = 0; c < 4; ++c) {
            const float p0 = __expf(sv[c][0] - m);
            const float p1 = __expf(sv[c][1] - m);
            const float p2 = __expf(sv[c][2] - m);
            const float p3 = __expf(sv[c][3] - m);
            tsc[c] = (p0 + p1) + (p2 + p3);
            ushort4 pk;
            pk.x = (ushort)bf16_bits(p0); pk.y = (ushort)bf16_bits(p1);
            pk.z = (ushort)bf16_bits(p2); pk.w = (ushort)bf16_bits(p3);
            *reinterpret_cast<ushort4*>(&p_lds[wid][l15][c * 16 + g * 4]) = pk;
        }
        float ts = (tsc[0] + tsc[1]) + (tsc[2] + tsc[3]);
        ts += __shfl_xor(ts, 16);
        ts += __shfl_xor(ts, 32);
        l = l * corr + ts;

        const short8v pb0 = *reinterpret_cast<const short8v*>(&p_lds[wid][l15][g * 8]);
        const short8v pb1 = *reinterpret_cast<const short8v*>(&p_lds[wid][l15][32 + g * 8]);

        // ---- PV swapped from LDS ----
        #pragma unroll
        for (int ht = 0; ht < 4; ++ht) {
            const short8v vf0 = *reinterpret_cast<const short8v*>(&V_lds[cur][ht * 16 + l15][g * 8]);
            const short8v vf1 = *reinterpret_cast<const short8v*>(&V_lds[cur][ht * 16 + l15][32 + g * 8]);
            accO[ht] = __builtin_amdgcn_mfma_f32_16x16x32_bf16(vf0, pb0, accO[ht], 0, 0, 0);
            accO[ht] = __builtin_amdgcn_mfma_f32_16x16x32_bf16(vf1, pb1, accO[ht], 0, 0, 0);
        }

        if (havenext) {
            #pragma unroll
            for (int j = 0; j < 2; ++j) {
                *reinterpret_cast<short8v*>(&K_lds[nxt][srow[j]][sseg[j] * 8]) = kreg[j];
                *reinterpret_cast<short8v*>(&V_lds[nxt][srow[j]][sseg[j] * 8]) = vreg[j];
            }
        }
        __syncthreads();
    }

    // ---- partial store: bf16, one ushort4 per ht ----
    ushort* po = pOb + (size_t)blockIdx.x * (64 * 64);
    #pragma unroll
    for (int ht = 0; ht < 4; ++ht) {
        ushort4 ov;
        ov.x = (ushort)bf16_bits(accO[ht][0]);
        ov.y = (ushort)bf16_bits(accO[ht][1]);
        ov.z = (ushort)bf16_bits(accO[ht][2]);
        ov.w = (ushort)bf16_bits(accO[ht][3]);
        *reinterpret_cast<ushort4*>(&po[(wid * 16 + l15) * 64 + ht * 16 + g * 4]) = ov;
    }
    if (g == 0) {
        pML[(size_t)blockIdx.x * 128 + wid * 16 + l15]      = m;
        pML[(size_t)blockIdx.x * 128 + 64 + wid * 16 + l15] = l;
    }
}

// ---------------------------------------------------------------------------
// Kernel 2b: merge partials, flattened: 512 blocks x 1024 thr, one thread
// per (row 0..15, h 0..63); only the nch-loop remains per thread.  pO bf16.
// ---------------------------------------------------------------------------
__global__ __launch_bounds__(1024) void attn_merge(
    const ushort* __restrict__ pOb,
    const float* __restrict__ pML,
    float* __restrict__ out)
{
    const int b  = blockIdx.x >> 7;
    const int qt = blockIdx.x & 127;
    const int qg = qt >> 2;
    const int t  = qg >> 2;
    const int s  = qg & 3;
    const int base = b * UPB2 + 2 * t * (t + 1) + s * (t + 1);
    const int nch  = t + 1;
    const int rowblk = (qt & 3) * 16;

    const int row = threadIdx.x >> 6;     // 0..15
    const int h   = threadIdx.x & 63;

    float M = -1e30f;
    for (int u = 0; u < nch; ++u)
        M = fmaxf(M, pML[(size_t)(base + u) * 128 + rowblk + row]);
    float O = 0.f, L = 0.f;
    for (int u = 0; u < nch; ++u) {
        const float w = __expf(pML[(size_t)(base + u) * 128 + rowblk + row] - M);
        O += w * bf16_val(pOb[(size_t)(base + u) * 4096 + (rowblk + row) * 64 + h]);
        L += w * pML[(size_t)(base + u) * 128 + 64 + rowblk + row];
    }
    out[((size_t)(b * T_ + qt * 16 + row)) * H_ + h] = O / L;
}

// ---------------------------------------------------------------------------
// Launch. Input order is setup_inputs() dict order: x, Wk, Wq, Wv.
// ws: qb 1MB | kb 1MB | vtp 1MB | wtf 384KB | pOb 4.7MB | pML 295KB (~8.4MB).
// ---------------------------------------------------------------------------
extern "C" void kernel_launch(void* const* d_in, const int* in_sizes, int n_in,
                              void* d_out, int out_size, void* d_ws, size_t ws_size,
                              hipStream_t stream)
{
    const float* x  = (const float*)d_in[0];
    const float* Wk = (const float*)d_in[1];
    const float* Wq = (const float*)d_in[2];
    const float* Wv = (const float*)d_in[3];
    float* out = (float*)d_out;

    ushort* qbp = (ushort*)d_ws;                    // [M][64]
    ushort* kbp = qbp + (size_t)M_ * H_;            // [M][64]
    ushort* vtp = kbp + (size_t)M_ * H_;            // [B][64][T]
    ushort* wtf = vtp + (size_t)B_ * H_ * T_;       // fragment-linear weights
    ushort* pOb = wtf + (size_t)3 * H_ * C_;        // [NBLK][64][64] bf16
    float*  pML = (float*)(pOb + (size_t)NBLK * 64 * 64);  // [NBLK][128]

    w_transpose<<<dim3(96), dim3(256), 0, stream>>>(Wq, Wk, Wv, wtf);
    qkv_mfma<<<dim3(M_ / 32), dim3(768), 0, stream>>>(x, wtf, qbp, kbp, vtp);
    attn_part<<<dim3(NBLK), dim3(256), 0, stream>>>(qbp, kbp, vtp, pOb, pML);
    attn_merge<<<dim3(128 * B_), dim3(1024), 0, stream>>>(pOb, pML, out);
}